// Round 14
// baseline (219.070 us; speedup 1.0000x reference)
//
#include <hip/hip_runtime.h>
#include <hip/hip_bf16.h>
#include <math.h>

// Problem constants
#define BGR 8        // graphs
#define PP 4096      // points per graph
#define NPTS 32768   // B*P
#define KNN 20
#define LCOV 10
#define FF 32
#define KS 5
#define NCLS 40
#define NGROUP 24    // 3*B, rows of ys
#define GROUPLEN 131072  // P*F flat elements per group

// KNN tiling: 256 blocks x 1024 threads; thread = (eighth 0..7, pt 0..127)
#define SPLIT 8
#define CHUNK (PP / SPLIT)        // 512 candidates per thread
#define PTSBLK 128                // points per block
#define KTHR 1024
#define NSLOT (KNN + 1)           // 21-slot network (self-point absorbable)
#define MPAD NSLOT                // merge-list stride 21: gcd(21,32)=1
#define SENT 0xFFFFFFFFu
#define SCELLS 4096
#define SCAP 12                   // LDS scratch slots per lane

// ---------------------------------------------------------------------------
// R28 vs R27 (200.3us, knn 95): knn measured 95 vs 80 with BYTE-IDENTICAL
// code (R26) — run-to-run noise ±15% (clock/env). knn tuning is below the
// noise floor; totals plateau ~197-203. Target the non-knn ~105us:
//  (a) BN stats via ATOMICS: spline atomicAdds its per-block (sum,sumsq)[64]
//      into a 64-float global accum (hipMemsetAsync-zeroed; graph-capture
//      legal — harness reset uses it). Kills ys's per-block 512KB stats
//      reduce (~13us of latency-exposed loads x 192 blocks). 2048 adds per
//      address over spline's ~15us = 1/7ns — negligible contention; float
//      reorder only perturbs rounding (tol 0.0156).
//  (b) ys occupancy: YSPLIT 8->32 (768 blocks = 3 waves/SIMD vs 0.75);
//      main loop 64 -> 16 dependent-load iters (5 triples + 1; stride-256
//      == 64 mod 96 rotation unchanged -> fj/cj/dj machinery verbatim).
//      head sums 32 partials.
// knn/spline compute bodies untouched. Expected total ~178-190; null =>
// ys was small, remainder is spline+gaps => near practical floor.
// ---------------------------------------------------------------------------
__device__ inline unsigned umn(unsigned a, unsigned b) { return a < b ? a : b; }
__device__ inline unsigned umx(unsigned a, unsigned b) { return a > b ? a : b; }

__device__ inline void mat3vec(const float M[9], const float v[3], float w[3]) {
    w[0] = M[0] * v[0] + M[1] * v[1] + M[2] * v[2];
    w[1] = M[3] * v[0] + M[4] * v[1] + M[5] * v[2];
    w[2] = M[6] * v[0] + M[7] * v[1] + M[8] * v[2];
}

__device__ inline float pi3(const float M[9], float v[3]) {
    v[0] = v[1] = v[2] = 0.57735026918962576f;  // 3^-0.5 as f32
#pragma unroll
    for (int it = 0; it < 5; ++it) {
        float w[3];
        mat3vec(M, v, w);
        float nrm = sqrtf(w[0] * w[0] + w[1] * w[1] + w[2] * w[2]) + 1e-12f;
        v[0] = w[0] / nrm;
        v[1] = w[1] / nrm;
        v[2] = w[2] / nrm;
    }
    float w[3];
    mat3vec(M, v, w);
    return v[0] * w[0] + v[1] * w[1] + v[2] * w[2];
}

__global__ __launch_bounds__(KTHR, 4) void knn_kernel(
    const float* __restrict__ pos, unsigned short* __restrict__ nbr16,
    float* __restrict__ Rbuf, float* __restrict__ v3out) {
    __shared__ float smem[4 * PP];           // 64 KB arena
    __shared__ unsigned short mOrig[PP];     // Morton slot -> original local idx
    __shared__ unsigned samp[PTSBLK * 24];   // 12 KB: 8 eighths x 3 keys / point
    __shared__ float Tseed[PTSBLK];
    __shared__ unsigned scr[KTHR / 64][SCAP][64];  // 48 KB accept scratch
    float* tx = smem;                // scan: -2x (ORIGINAL order) | merge: mk
    float* ty = smem + PP;
    float* tz = smem + 2 * PP;
    float* tw = smem + 3 * PP;       // |q|^2 (dead after scan)
    unsigned short* lnbr = (unsigned short*)(smem + 3 * PP + 2816);

    int b = blockIdx.x >> 5;          // 32 blocks per graph
    int blkInGraph = blockIdx.x & 31;
    const float* gp = pos + (size_t)b * PP * 3;
    int tid = threadIdx.x;
    int lane = tid & 63;
    int wid = tid >> 6;

    // ---- Phase A: Morton-cell counting sort (per-block, overlays arena) ----
    {
        unsigned* cnt = (unsigned*)smem;                         // words 0..4095
        unsigned short* cellOf = (unsigned short*)(smem + 4096); // words 4096..6143
        unsigned* tsum = (unsigned*)(smem + 6144);               // words 6144..7167
        for (int i = tid; i < SCELLS; i += KTHR) cnt[i] = 0u;
        __syncthreads();
        for (int i = tid; i < PP; i += KTHR) {
            float x = gp[i * 3 + 0];
            float y = gp[i * 3 + 1];
            float z = gp[i * 3 + 2];
            int cx = min(max((int)floorf((x + 4.0f) * 2.0f), 0), 15);
            int cy = min(max((int)floorf((y + 4.0f) * 2.0f), 0), 15);
            int cz = min(max((int)floorf((z + 4.0f) * 2.0f), 0), 15);
            unsigned m = 0;
#pragma unroll
            for (int bb = 0; bb < 4; ++bb)
                m |= (((unsigned)(cx >> bb) & 1u) << (3 * bb + 2)) |
                     (((unsigned)(cy >> bb) & 1u) << (3 * bb + 1)) |
                     (((unsigned)(cz >> bb) & 1u) << (3 * bb + 0));
            cellOf[i] = (unsigned short)m;
            atomicAdd(&cnt[m], 1u);
        }
        __syncthreads();
        unsigned c0 = cnt[4 * tid + 0];
        unsigned c1 = cnt[4 * tid + 1];
        unsigned c2 = cnt[4 * tid + 2];
        unsigned c3 = cnt[4 * tid + 3];
        unsigned local = c0 + c1 + c2 + c3;
        tsum[tid] = local;
        __syncthreads();
        for (int off = 1; off < 1024; off <<= 1) {
            unsigned v = (tid >= off) ? tsum[tid - off] : 0u;
            __syncthreads();
            tsum[tid] += v;
            __syncthreads();
        }
        unsigned base = tsum[tid] - local;   // exclusive prefix
        cnt[4 * tid + 0] = base;
        cnt[4 * tid + 1] = base + c0;
        cnt[4 * tid + 2] = base + c0 + c1;
        cnt[4 * tid + 3] = base + c0 + c1 + c2;
        __syncthreads();
        for (int i = tid; i < PP; i += KTHR) {
            unsigned dst = atomicAdd(&cnt[cellOf[i]], 1u);
            mOrig[dst] = (unsigned short)i;
        }
    }
    __syncthreads();

    // ---- Phase B: stage scan arrays in ORIGINAL order ----
    for (int i = tid; i < PP; i += KTHR) {
        float x = gp[i * 3 + 0];
        float y = gp[i * 3 + 1];
        float z = gp[i * 3 + 2];
        tx[i] = -2.0f * x;
        ty[i] = -2.0f * y;
        tz[i] = -2.0f * z;
        tw[i] = x * x + y * y + z * z;
    }
    __syncthreads();

    int eighth = tid >> 7;                // 0..7 (wave-uniform)
    int pt = tid & (PTSBLK - 1);          // 0..127
    int qSlot = blkInGraph * PTSBLK + pt; // query's Morton slot in graph
    int li = mOrig[qSlot];                // ORIGINAL local point index
    float px = -0.5f * tx[li];
    float py = -0.5f * ty[li];
    float pz = -0.5f * tz[li];
    float p2 = tw[li];
    int jbeg = eighth * CHUNK;

    // ---- seed: top-3 of 32 chunks x 4 consecutive slots (float4 loads) ----
    {
        unsigned s0 = SENT, s1 = SENT, s2 = SENT;
#pragma unroll 4
        for (int c = 0; c < 32; ++c) {
            int base = jbeg + c * 16;     // 4-aligned; max base+3 = jbeg+499
            float4 xv = *(const float4*)(tx + base);
            float4 yv = *(const float4*)(ty + base);
            float4 zv = *(const float4*)(tz + base);
            float4 wv = *(const float4*)(tw + base);
            float xa[4] = {xv.x, xv.y, xv.z, xv.w};
            float ya[4] = {yv.x, yv.y, yv.z, yv.w};
            float za[4] = {zv.x, zv.y, zv.z, zv.w};
            float wa[4] = {wv.x, wv.y, wv.z, wv.w};
#pragma unroll
            for (int u = 0; u < 4; ++u) {
                float dh = fmaf(px, xa[u], fmaf(py, ya[u], fmaf(pz, za[u], wa[u])));
                float d = fmaxf(dh + p2, 0.0f);
                unsigned key = (__float_as_uint(d) & 0xFFFFF000u)
                               | (unsigned)(base + u);
                if (base + u == li) key = SENT;   // self excluded
                unsigned t0 = umn(key, s0); key = umx(key, s0); s0 = t0;
                t0 = umn(key, s1); key = umx(key, s1); s1 = t0;
                s2 = umn(key, s2);
            }
        }
        unsigned* sdst = &samp[pt * 24 + eighth * 3];
        sdst[0] = s0; sdst[1] = s1; sdst[2] = s2;
    }
    __syncthreads();
    if (tid < PTSBLK) {
        // T = 21st smallest of 24 = 4th largest; +2 trunc-ulps headroom.
        unsigned g0 = 0, g1 = 0, g2 = 0, g3 = 0;
        const unsigned* ss = &samp[tid * 24];
#pragma unroll
        for (int i = 0; i < 24; ++i) {
            unsigned k = ss[i], a;
            a = umx(k, g0); k = umn(k, g0); g0 = a;
            a = umx(k, g1); k = umn(k, g1); g1 = a;
            a = umx(k, g2); k = umn(k, g2); g2 = a;
            g3 = umx(k, g3);
        }
        Tseed[tid] = __uint_as_float((g3 & 0xFFFFF000u) + 0x2000u);
    }
    __syncthreads();
    float seed_hat = Tseed[pt] - p2;

    unsigned bd[NSLOT];
#pragma unroll
    for (int k = 0; k < NSLOT; k++) bd[k] = SENT;
    float worst_hat = seed_hat;

    unsigned* scrW = &scr[wid][0][0];
    unsigned cnt = 0;

    auto drain = [&]() {
#pragma unroll
        for (int s = 0; s < SCAP; ++s) {
            if (!__any((int)cnt > s)) break;   // monotone fill 0..cnt-1
            unsigned k = (s < (int)cnt) ? scrW[s * 64 + lane] : SENT;
#pragma unroll
            for (int i = 0; i < NSLOT; i++) {
                unsigned lo = umn(k, bd[i]);   // v_min_u32
                k = umx(k, bd[i]);             // v_max_u32
                bd[i] = lo;
            }
        }
        cnt = 0;
        unsigned wb = bd[NSLOT - 1];
        float nw = (wb == SENT) ? INFINITY
                                : __uint_as_float(wb & 0xFFFFF000u) - p2;
        worst_hat = fminf(nw, seed_hat);
    };

    // ---- flat scan, ORIGINAL order, 8-wide (loads batched, 1 ballot/8) ----
    for (int jj = jbeg; jj < jbeg + CHUNK; jj += 8) {
        float4 xv0 = *(const float4*)(tx + jj);
        float4 yv0 = *(const float4*)(ty + jj);
        float4 zv0 = *(const float4*)(tz + jj);
        float4 wv0 = *(const float4*)(tw + jj);
        float4 xv1 = *(const float4*)(tx + jj + 4);
        float4 yv1 = *(const float4*)(ty + jj + 4);
        float4 zv1 = *(const float4*)(tz + jj + 4);
        float4 wv1 = *(const float4*)(tw + jj + 4);
        float xa[8] = {xv0.x, xv0.y, xv0.z, xv0.w, xv1.x, xv1.y, xv1.z, xv1.w};
        float ya[8] = {yv0.x, yv0.y, yv0.z, yv0.w, yv1.x, yv1.y, yv1.z, yv1.w};
        float za[8] = {zv0.x, zv0.y, zv0.z, zv0.w, zv1.x, zv1.y, zv1.z, zv1.w};
        float wa[8] = {wv0.x, wv0.y, wv0.z, wv0.w, wv1.x, wv1.y, wv1.z, wv1.w};
#pragma unroll
        for (int u = 0; u < 8; u++) {
            float dh = fmaf(px, xa[u], fmaf(py, ya[u], fmaf(pz, za[u], wa[u])));
            if (dh < worst_hat) {
                float d = fmaxf(dh + p2, 0.0f);
                scrW[cnt * 64 + lane] = (__float_as_uint(d) & 0xFFFFF000u)
                                        | (unsigned)(jj + u);
                cnt++;
            }
        }
        if (__any(cnt >= 4u)) drain();   // cap-12 safe: <=3 carry + 8/iter
    }
    drain();

    // ---- 8-way merge, two 64-point phases; emits global nbr16 + LDS lnbr ---
    __syncthreads();
    unsigned* mk = (unsigned*)smem;    // words 0..10751
    for (int h = 0; h < 2; h++) {
        if ((pt >> 6) == h) {
            int lpt = pt & 63;
#pragma unroll
            for (int k = 0; k < NSLOT; k++)
                mk[(eighth * 64 + lpt) * MPAD + k] = bd[k];
        }
        __syncthreads();
        if (tid < 64) {
            int p = tid;
            const unsigned* base = &mk[p * MPAD];
            int cur[SPLIT];
#pragma unroll
            for (int q = 0; q < SPLIT; q++) cur[q] = 0;
            int lpt2 = h * 64 + p;
            int gi = b * PP + (int)mOrig[blkInGraph * PTSBLK + lpt2];
#pragma unroll
            for (int t = 0; t < NSLOT; t++) {
                unsigned v[SPLIT];
#pragma unroll
                for (int q = 0; q < SPLIT; q++)
                    v[q] = base[q * 64 * MPAD + cur[q]];
                unsigned m = v[0];
#pragma unroll
                for (int q = 1; q < SPLIT; q++) m = umn(m, v[q]);
                if (t > 0) {
                    int local = (int)(m & 0xFFFu);   // original local idx
                    nbr16[(size_t)gi * KNN + (t - 1)] = (unsigned short)local;
                    lnbr[lpt2 * KNN + (t - 1)] = (unsigned short)local;
                }
#pragma unroll
                for (int q = 0; q < SPLIT; q++) cur[q] += (v[q] == m);
            }
        }
        __syncthreads();
    }

    // ---- re-stage RAW coords in ORIGINAL order (L2-hot) for the eig tail ----
    for (int i = tid; i < PP; i += KTHR) {
        tx[i] = gp[i * 3 + 0];
        ty[i] = gp[i * 3 + 1];
        tz[i] = gp[i * 3 + 2];
    }
    __syncthreads();

    // ---- eig tail: threads 0..127, one point each, all data in LDS ----
    if (tid < PTSBLK) {
        int lp = tid;
        int ng = mOrig[blkInGraph * PTSBLK + lp];   // ORIGINAL local idx
        int n = b * PP + ng;
        float qx = tx[ng], qy = ty[ng], qz = tz[ng];
        const unsigned short* ln = &lnbr[lp * KNN];

        float m00 = 0.f, m01 = 0.f, m02 = 0.f, m11 = 0.f, m12 = 0.f, m22 = 0.f;
#pragma unroll
        for (int k = 0; k < LCOV; k++) {
            int id = ln[k];
            float cx = tx[id] - qx;
            float cy = ty[id] - qy;
            float cz = tz[id] - qz;
            m00 += cx * cx; m01 += cx * cy; m02 += cx * cz;
            m11 += cy * cy; m12 += cy * cz; m22 += cz * cz;
        }
        float M[9] = {m00, m01, m02, m01, m11, m12, m02, m12, m22};

        float v1[3], v2[3], v3[3];
        float l1 = pi3(M, v1);
        float M2[9];
#pragma unroll
        for (int c = 0; c < 3; c++)
#pragma unroll
            for (int d = 0; d < 3; d++)
                M2[c * 3 + d] = M[c * 3 + d] - l1 * v1[c] * v1[d];
        pi3(M2, v2);
        v3[0] = v1[1] * v2[2] - v1[2] * v2[1];
        v3[1] = v1[2] * v2[0] - v1[0] * v2[2];
        v3[2] = v1[0] * v2[1] - v1[1] * v2[0];
        {
            float nrm = sqrtf(v3[0] * v3[0] + v3[1] * v3[1] + v3[2] * v3[2]) + 1e-12f;
            v3[0] /= nrm; v3[1] /= nrm; v3[2] /= nrm;
        }

        float ssum = 0.f, mx = 0.f;
#pragma unroll
        for (int k = 0; k < KNN; k++) {
            int id = ln[k];
            float cx = tx[id] - qx;
            float cy = ty[id] - qy;
            float cz = tz[id] - qz;
            float d0 = cx * v1[0] + cy * v1[1] + cz * v1[2];
            float d1 = cx * v2[0] + cy * v2[1] + cz * v2[2];
            float d2 = cx * v3[0] + cy * v3[1] + cz * v3[2];
            ssum += d2;
            mx = fmaxf(mx, fabsf(d0));
            mx = fmaxf(mx, fabsf(d1));
            mx = fmaxf(mx, fabsf(d2));
        }
        float sgn = (ssum > 0.f) ? 1.f : ((ssum < 0.f) ? -1.f : 0.f);

        float sc = 2.0f / mx;
        float* R = Rbuf + (size_t)n * 12;
        R[0] = v1[0] * sc;  R[1] = v1[1] * sc;  R[2] = v1[2] * sc;
        R[3] = v2[0] * sc;  R[4] = v2[1] * sc;  R[5] = v2[2] * sc;
        float s2 = sgn * sc;
        R[6] = v3[0] * s2;  R[7] = v3[1] * s2;  R[8] = v3[2] * s2;
        R[9] = 0.f; R[10] = 0.f; R[11] = 0.f;

        v3out[n * 3 + 0] = v3[0];
        v3out[n * 3 + 1] = v3[1];
        v3out[n * 3 + 2] = v3[2];
    }
}

// ---------------------------------------------------------------------------
// Kernel 2: spline conv; BN partials ATOMICALLY accumulated into accum[64]
// (accum[0..31] = sum per f, accum[32..63] = sumsq per f).
// ---------------------------------------------------------------------------
#define NPB 16
#define SPLBLKS (NPTS / NPB)   // 2048
__global__ __launch_bounds__(512) void spline_kernel(
    const float* __restrict__ pos, const unsigned short* __restrict__ nbr16,
    const float* __restrict__ Rbuf, const float* __restrict__ Wsp,
    const float* __restrict__ root, const float* __restrict__ bias,
    float* __restrict__ node, float* __restrict__ sums_accum) {
    __shared__ float wbuf[NPB * KNN * 8];    // packed w' per (pt,k,s); reused

    int tid = threadIdx.x;
    if (tid < NPB * KNN) {              // 320 phase-1 threads
        int pt = tid / KNN;
        int k = tid - pt * KNN;
        int n = blockIdx.x * NPB + pt;
        const float4* Rv = (const float4*)(Rbuf + (size_t)n * 12);
        float4 r0 = Rv[0], r1 = Rv[1], r2 = Rv[2];
        float px = pos[n * 3 + 0], py = pos[n * 3 + 1], pz = pos[n * 3 + 2];
        int id = (n & ~(PP - 1)) | (int)nbr16[(size_t)n * KNN + k];
        float cxx = pos[id * 3 + 0] - px;
        float cyy = pos[id * 3 + 1] - py;
        float czz = pos[id * 3 + 2] - pz;
        float v0 = fmaf(cxx, r0.x, fmaf(cyy, r0.y, fmaf(czz, r0.z, 2.0f)));
        float v1 = fmaf(cxx, r0.w, fmaf(cyy, r1.x, fmaf(czz, r1.y, 2.0f)));
        float v2 = fmaf(cxx, r1.z, fmaf(cyy, r1.w, fmaf(czz, r2.x, 2.0f)));
        float f0 = floorf(v0), f1 = floorf(v1), f2 = floorf(v2);
        float fr0 = v0 - f0, fr1 = v1 - f1, fr2 = v2 - f2;
        int fi0 = (int)f0, fi1 = (int)f1, fi2 = (int)f2;
        float* wdst = &wbuf[(pt * KNN + k) * 8];
#pragma unroll
        for (int s = 0; s < 8; s++) {
            int b0 = (s >> 2) & 1, b1 = (s >> 1) & 1, b2s = s & 1;
            int i0 = min(max(fi0 + b0, 0), KS - 1);
            int i1 = min(max(fi1 + b1, 0), KS - 1);
            int i2 = min(max(fi2 + b2s, 0), KS - 1);
            float w = (b0 ? fr0 : 1.f - fr0) * (b1 ? fr1 : 1.f - fr1) *
                      (b2s ? fr2 : 1.f - fr2);
            unsigned flat = (unsigned)((i0 * KS + i1) * KS + i2);
            wdst[s] = __uint_as_float((__float_as_uint(w) & ~127u) | flat);
        }
    }
    __syncthreads();

    // phase 2: thread = (pt, f); Wsp read direct (L1-resident, coalesced)
    int pt = tid >> 5;
    int f = tid & 31;
    const float* wrow = &wbuf[pt * (KNN * 8)];
    float acc = 0.f;
#pragma unroll
    for (int k = 0; k < KNN; k++) {
        float4 wa = *(const float4*)&wrow[k * 8];
        float4 wb = *(const float4*)&wrow[k * 8 + 4];
        float wv[8] = {wa.x, wa.y, wa.z, wa.w, wb.x, wb.y, wb.z, wb.w};
#pragma unroll
        for (int s = 0; s < 8; s++) {
            unsigned u = __float_as_uint(wv[s]) & 127u;
            acc = fmaf(wv[s], Wsp[u * FF + f], acc);
        }
    }
    int n = blockIdx.x * NPB + pt;
    float val = acc * (1.0f / KNN) + root[f] + bias[f];
    node[(size_t)n * FF + f] = val;

    // ---- per-block bn partial -> global atomic accumulate ----
    __syncthreads();                 // wbuf reads done; safe to reuse
    wbuf[tid] = val;
    wbuf[512 + tid] = val * val;
    __syncthreads();
    if (tid < 64) {
        int ff = tid & 31;
        int off = (tid >> 5) * 512;  // 0 = sum, 512 = sumsq
        float s = 0.f;
#pragma unroll
        for (int p = 0; p < NPB; p++) s += wbuf[off + p * 32 + ff];
        atomicAdd(&sums_accum[tid], s);
    }
}

// ---------------------------------------------------------------------------
// Kernel 3: BN apply + sigmoid + reduce to ys partials (YSPLIT=32: 768
// blocks = 3 waves/SIMD; 16 elements/thread = 5 triples + 1).
// ---------------------------------------------------------------------------
#define YSPLIT 32
#define YCHUNK (GROUPLEN / YSPLIT)   // 4096
__global__ __launch_bounds__(256) void ys_kernel(
    const float* __restrict__ node, const float* __restrict__ v3,
    const float* __restrict__ sums_accum, const float* __restrict__ gamma,
    const float* __restrict__ beta, float* __restrict__ ys_part) {
    __shared__ float sa[FF], sb[FF];
    if (threadIdx.x < FF) {
        int f = threadIdx.x;
        float mu = sums_accum[f] * (1.0f / NPTS);
        float var = sums_accum[FF + f] * (1.0f / NPTS) - mu * mu;
        float inv = 1.0f / sqrtf(var + 1e-5f);
        sa[f] = gamma[f] * inv;
        sb[f] = beta[f] - gamma[f] * inv * mu;
    }
    __syncthreads();

    int g = blockIdx.x >> 5;
    int sub = blockIdx.x & 31;
    int t0 = g * GROUPLEN + sub * YCHUNK + threadIdx.x;
    int n = t0 / 96;
    int r0 = t0 - n * 96;
    int rj[3], fj[3], cj[3], dj[3];
    rj[0] = r0;
    rj[1] = (r0 + 64) % 96;
    rj[2] = (r0 + 32) % 96;
#pragma unroll
    for (int j = 0; j < 3; j++) {
        fj[j] = rj[j] / 3;
        cj[j] = rj[j] - fj[j] * 3;
        dj[j] = (rj[j] >= 32) ? 3 : 2;
    }
    float Sa0 = sa[fj[0]], Sb0 = sb[fj[0]];
    float Sa1 = sa[fj[1]], Sb1 = sb[fj[1]];
    float Sa2 = sa[fj[2]], Sb2 = sb[fj[2]];
    int nf = n * FF;
    int n3 = n * 3;

    float acc = 0.f;
#pragma unroll 1
    for (int tr = 0; tr < 5; tr++) {
        {
            float xb = fmaf(Sa0, node[nf + fj[0]], Sb0);
            float val = xb * v3[n3 + cj[0]];
            acc += 1.0f / (1.0f + __expf(-val));
            nf += dj[0] * FF; n3 += dj[0] * 3;
        }
        {
            float xb = fmaf(Sa1, node[nf + fj[1]], Sb1);
            float val = xb * v3[n3 + cj[1]];
            acc += 1.0f / (1.0f + __expf(-val));
            nf += dj[1] * FF; n3 += dj[1] * 3;
        }
        {
            float xb = fmaf(Sa2, node[nf + fj[2]], Sb2);
            float val = xb * v3[n3 + cj[2]];
            acc += 1.0f / (1.0f + __expf(-val));
            nf += dj[2] * FF; n3 += dj[2] * 3;
        }
    }
    {
        float xb = fmaf(Sa0, node[nf + fj[0]], Sb0);
        float val = xb * v3[n3 + cj[0]];
        acc += 1.0f / (1.0f + __expf(-val));
    }

    __shared__ float red[256];
    red[threadIdx.x] = acc;
    __syncthreads();
    if (threadIdx.x < FF) {
        float s = 0.f;
        for (int t = threadIdx.x; t < 256; t += FF) s += red[t];
        ys_part[(sub * NGROUP + g) * FF + threadIdx.x] = s * (1.0f / PP);
    }
}

// ---------------------------------------------------------------------------
// Kernel 4: MLP head; sums the 32 ys partials while loading syr.
// ---------------------------------------------------------------------------
__global__ __launch_bounds__(256) void head_kernel(
    const float* __restrict__ ys_part, const float* __restrict__ W1,
    const float* __restrict__ b1, const float* __restrict__ W2,
    const float* __restrict__ b2, float* __restrict__ out) {
    int g = blockIdx.x;
    __shared__ float syr[FF];
    __shared__ float h[256];
    __shared__ float logits[NCLS];
    __shared__ float mstat[2];
    if (threadIdx.x < FF) {
        float s = 0.f;
#pragma unroll
        for (int sub = 0; sub < YSPLIT; sub++)
            s += ys_part[(sub * NGROUP + g) * FF + threadIdx.x];
        syr[threadIdx.x] = s;
    }
    __syncthreads();
    int j = threadIdx.x;
    float acc = b1[j];
#pragma unroll
    for (int f = 0; f < FF; f++) acc += syr[f] * W1[f * 256 + j];
    h[j] = acc > 0.f ? acc : expm1f(acc);
    __syncthreads();
    if (j < NCLS) {
        float l = b2[j];
        for (int q = 0; q < 256; q++) l += h[q] * W2[q * NCLS + j];
        logits[j] = l;
    }
    __syncthreads();
    if (j == 0) {
        float m = -INFINITY;
        for (int o = 0; o < NCLS; o++) m = fmaxf(m, logits[o]);
        float s = 0.f;
        for (int o = 0; o < NCLS; o++) s += expf(logits[o] - m);
        mstat[0] = m;
        mstat[1] = logf(s);
    }
    __syncthreads();
    if (j < NCLS) out[g * NCLS + j] = logits[j] - mstat[0] - mstat[1];
}

// ---------------------------------------------------------------------------
extern "C" void kernel_launch(void* const* d_in, const int* in_sizes, int n_in,
                              void* d_out, int out_size, void* d_ws, size_t ws_size,
                              hipStream_t stream) {
    const float* pos   = (const float*)d_in[0];
    const float* Wsp   = (const float*)d_in[1];
    const float* root  = (const float*)d_in[2];
    const float* bias  = (const float*)d_in[3];
    const float* gamma = (const float*)d_in[4];
    const float* beta  = (const float*)d_in[5];
    const float* W1    = (const float*)d_in[6];
    const float* b1    = (const float*)d_in[7];
    const float* W2    = (const float*)d_in[8];
    const float* b2    = (const float*)d_in[9];
    float* out = (float*)d_out;

    char* ws = (char*)d_ws;
    unsigned short* nbr16 = (unsigned short*)(ws);     // 32768*20*2 = 1310720
    float* sums_accum = (float*)(ws + 1310720);        // 64*4 = 256
    float* ys_part   = (float*)(ws + 1835008);         // 32*24*32*4 = 98304
    float* node = (float*)(ws + 2621440);              // 32768*32*4 = 4194304
    float* v3   = (float*)(ws + 6815744);              // 32768*3*4  = 393216
    float* Rbuf = (float*)(ws + 7212288);              // 32768*12*4 = 1572864

    hipMemsetAsync(sums_accum, 0, 64 * sizeof(float), stream);
    knn_kernel<<<256, KTHR, 0, stream>>>(pos, nbr16, Rbuf, v3);
    spline_kernel<<<SPLBLKS, 512, 0, stream>>>(pos, nbr16, Rbuf, Wsp, root,
                                               bias, node, sums_accum);
    ys_kernel<<<NGROUP * YSPLIT, 256, 0, stream>>>(node, v3, sums_accum, gamma,
                                                   beta, ys_part);
    head_kernel<<<NGROUP, 256, 0, stream>>>(ys_part, W1, b1, W2, b2, out);
}

// Round 15
// 192.807 us; speedup vs baseline: 1.1362x; 1.1362x over previous
//
#include <hip/hip_runtime.h>
#include <hip/hip_bf16.h>
#include <math.h>

// Problem constants
#define BGR 8        // graphs
#define PP 4096      // points per graph
#define NPTS 32768   // B*P
#define KNN 20
#define LCOV 10
#define FF 32
#define KS 5
#define NCLS 40
#define NGROUP 24    // 3*B, rows of ys
#define GROUPLEN 131072  // P*F flat elements per group

// KNN tiling: 256 blocks x 1024 threads; thread = (eighth 0..7, pt 0..127)
#define SPLIT 8
#define CHUNK (PP / SPLIT)        // 512 candidates per thread
#define PTSBLK 128                // points per block
#define KTHR 1024
#define NSLOT (KNN + 1)           // 21-slot network (self-point absorbable)
#define MPAD NSLOT                // merge-list stride 21: gcd(21,32)=1
#define SENT 0xFFFFFFFFu
#define SCELLS 4096
#define SCAP 12                   // LDS scratch slots per lane

// ---------------------------------------------------------------------------
// R29 vs R28 (219us; knn 79.5 fast-side, non-knn 105->139): R28's regression
// mechanism = SAME-LINE ATOMIC CONTENTION — 2048 blocks x 64 atomicAdds onto
// 64 addresses in 4 cache lines, device-scope across 8 XCDs (line migration
// + per-line serialization, bunched at block retire) ~ +35us. The ys
// restructure (YSPLIT=32) only removed work — innocent. Fix:
//  (a) spline reverts to PLAIN per-block (sum,sumsq)[64] stores (R27 path).
//  (b) tiny stats_kernel (64 blocks x 256, one column each) reduces the
//      512KB of partials ONCE (vs 192x redundant in R27, atomic in R28).
//      ~2-4us incl. launch (R26: kernel boundaries cheap; coop sync not).
//  (c) keep R28 ys (YSPLIT=32, 3 waves/SIMD, reads 64 floats) + head (32
//      partials). Memset dropped (stats_kernel overwrites).
// Pre-committed null read: total ~197-200 => R27's ys-stats was cheaper
// than modeled => practical plateau, declare next round.
// ---------------------------------------------------------------------------
__device__ inline unsigned umn(unsigned a, unsigned b) { return a < b ? a : b; }
__device__ inline unsigned umx(unsigned a, unsigned b) { return a > b ? a : b; }

__device__ inline void mat3vec(const float M[9], const float v[3], float w[3]) {
    w[0] = M[0] * v[0] + M[1] * v[1] + M[2] * v[2];
    w[1] = M[3] * v[0] + M[4] * v[1] + M[5] * v[2];
    w[2] = M[6] * v[0] + M[7] * v[1] + M[8] * v[2];
}

__device__ inline float pi3(const float M[9], float v[3]) {
    v[0] = v[1] = v[2] = 0.57735026918962576f;  // 3^-0.5 as f32
#pragma unroll
    for (int it = 0; it < 5; ++it) {
        float w[3];
        mat3vec(M, v, w);
        float nrm = sqrtf(w[0] * w[0] + w[1] * w[1] + w[2] * w[2]) + 1e-12f;
        v[0] = w[0] / nrm;
        v[1] = w[1] / nrm;
        v[2] = w[2] / nrm;
    }
    float w[3];
    mat3vec(M, v, w);
    return v[0] * w[0] + v[1] * w[1] + v[2] * w[2];
}

__global__ __launch_bounds__(KTHR, 4) void knn_kernel(
    const float* __restrict__ pos, unsigned short* __restrict__ nbr16,
    float* __restrict__ Rbuf, float* __restrict__ v3out) {
    __shared__ float smem[4 * PP];           // 64 KB arena
    __shared__ unsigned short mOrig[PP];     // Morton slot -> original local idx
    __shared__ unsigned samp[PTSBLK * 24];   // 12 KB: 8 eighths x 3 keys / point
    __shared__ float Tseed[PTSBLK];
    __shared__ unsigned scr[KTHR / 64][SCAP][64];  // 48 KB accept scratch
    float* tx = smem;                // scan: -2x (ORIGINAL order) | merge: mk
    float* ty = smem + PP;
    float* tz = smem + 2 * PP;
    float* tw = smem + 3 * PP;       // |q|^2 (dead after scan)
    unsigned short* lnbr = (unsigned short*)(smem + 3 * PP + 2816);

    int b = blockIdx.x >> 5;          // 32 blocks per graph
    int blkInGraph = blockIdx.x & 31;
    const float* gp = pos + (size_t)b * PP * 3;
    int tid = threadIdx.x;
    int lane = tid & 63;
    int wid = tid >> 6;

    // ---- Phase A: Morton-cell counting sort (per-block, overlays arena) ----
    {
        unsigned* cnt = (unsigned*)smem;                         // words 0..4095
        unsigned short* cellOf = (unsigned short*)(smem + 4096); // words 4096..6143
        unsigned* tsum = (unsigned*)(smem + 6144);               // words 6144..7167
        for (int i = tid; i < SCELLS; i += KTHR) cnt[i] = 0u;
        __syncthreads();
        for (int i = tid; i < PP; i += KTHR) {
            float x = gp[i * 3 + 0];
            float y = gp[i * 3 + 1];
            float z = gp[i * 3 + 2];
            int cx = min(max((int)floorf((x + 4.0f) * 2.0f), 0), 15);
            int cy = min(max((int)floorf((y + 4.0f) * 2.0f), 0), 15);
            int cz = min(max((int)floorf((z + 4.0f) * 2.0f), 0), 15);
            unsigned m = 0;
#pragma unroll
            for (int bb = 0; bb < 4; ++bb)
                m |= (((unsigned)(cx >> bb) & 1u) << (3 * bb + 2)) |
                     (((unsigned)(cy >> bb) & 1u) << (3 * bb + 1)) |
                     (((unsigned)(cz >> bb) & 1u) << (3 * bb + 0));
            cellOf[i] = (unsigned short)m;
            atomicAdd(&cnt[m], 1u);
        }
        __syncthreads();
        unsigned c0 = cnt[4 * tid + 0];
        unsigned c1 = cnt[4 * tid + 1];
        unsigned c2 = cnt[4 * tid + 2];
        unsigned c3 = cnt[4 * tid + 3];
        unsigned local = c0 + c1 + c2 + c3;
        tsum[tid] = local;
        __syncthreads();
        for (int off = 1; off < 1024; off <<= 1) {
            unsigned v = (tid >= off) ? tsum[tid - off] : 0u;
            __syncthreads();
            tsum[tid] += v;
            __syncthreads();
        }
        unsigned base = tsum[tid] - local;   // exclusive prefix
        cnt[4 * tid + 0] = base;
        cnt[4 * tid + 1] = base + c0;
        cnt[4 * tid + 2] = base + c0 + c1;
        cnt[4 * tid + 3] = base + c0 + c1 + c2;
        __syncthreads();
        for (int i = tid; i < PP; i += KTHR) {
            unsigned dst = atomicAdd(&cnt[cellOf[i]], 1u);
            mOrig[dst] = (unsigned short)i;
        }
    }
    __syncthreads();

    // ---- Phase B: stage scan arrays in ORIGINAL order ----
    for (int i = tid; i < PP; i += KTHR) {
        float x = gp[i * 3 + 0];
        float y = gp[i * 3 + 1];
        float z = gp[i * 3 + 2];
        tx[i] = -2.0f * x;
        ty[i] = -2.0f * y;
        tz[i] = -2.0f * z;
        tw[i] = x * x + y * y + z * z;
    }
    __syncthreads();

    int eighth = tid >> 7;                // 0..7 (wave-uniform)
    int pt = tid & (PTSBLK - 1);          // 0..127
    int qSlot = blkInGraph * PTSBLK + pt; // query's Morton slot in graph
    int li = mOrig[qSlot];                // ORIGINAL local point index
    float px = -0.5f * tx[li];
    float py = -0.5f * ty[li];
    float pz = -0.5f * tz[li];
    float p2 = tw[li];
    int jbeg = eighth * CHUNK;

    // ---- seed: top-3 of 32 chunks x 4 consecutive slots (float4 loads) ----
    {
        unsigned s0 = SENT, s1 = SENT, s2 = SENT;
#pragma unroll 4
        for (int c = 0; c < 32; ++c) {
            int base = jbeg + c * 16;     // 4-aligned; max base+3 = jbeg+499
            float4 xv = *(const float4*)(tx + base);
            float4 yv = *(const float4*)(ty + base);
            float4 zv = *(const float4*)(tz + base);
            float4 wv = *(const float4*)(tw + base);
            float xa[4] = {xv.x, xv.y, xv.z, xv.w};
            float ya[4] = {yv.x, yv.y, yv.z, yv.w};
            float za[4] = {zv.x, zv.y, zv.z, zv.w};
            float wa[4] = {wv.x, wv.y, wv.z, wv.w};
#pragma unroll
            for (int u = 0; u < 4; ++u) {
                float dh = fmaf(px, xa[u], fmaf(py, ya[u], fmaf(pz, za[u], wa[u])));
                float d = fmaxf(dh + p2, 0.0f);
                unsigned key = (__float_as_uint(d) & 0xFFFFF000u)
                               | (unsigned)(base + u);
                if (base + u == li) key = SENT;   // self excluded
                unsigned t0 = umn(key, s0); key = umx(key, s0); s0 = t0;
                t0 = umn(key, s1); key = umx(key, s1); s1 = t0;
                s2 = umn(key, s2);
            }
        }
        unsigned* sdst = &samp[pt * 24 + eighth * 3];
        sdst[0] = s0; sdst[1] = s1; sdst[2] = s2;
    }
    __syncthreads();
    if (tid < PTSBLK) {
        // T = 21st smallest of 24 = 4th largest; +2 trunc-ulps headroom.
        unsigned g0 = 0, g1 = 0, g2 = 0, g3 = 0;
        const unsigned* ss = &samp[tid * 24];
#pragma unroll
        for (int i = 0; i < 24; ++i) {
            unsigned k = ss[i], a;
            a = umx(k, g0); k = umn(k, g0); g0 = a;
            a = umx(k, g1); k = umn(k, g1); g1 = a;
            a = umx(k, g2); k = umn(k, g2); g2 = a;
            g3 = umx(k, g3);
        }
        Tseed[tid] = __uint_as_float((g3 & 0xFFFFF000u) + 0x2000u);
    }
    __syncthreads();
    float seed_hat = Tseed[pt] - p2;

    unsigned bd[NSLOT];
#pragma unroll
    for (int k = 0; k < NSLOT; k++) bd[k] = SENT;
    float worst_hat = seed_hat;

    unsigned* scrW = &scr[wid][0][0];
    unsigned cnt = 0;

    auto drain = [&]() {
#pragma unroll
        for (int s = 0; s < SCAP; ++s) {
            if (!__any((int)cnt > s)) break;   // monotone fill 0..cnt-1
            unsigned k = (s < (int)cnt) ? scrW[s * 64 + lane] : SENT;
#pragma unroll
            for (int i = 0; i < NSLOT; i++) {
                unsigned lo = umn(k, bd[i]);   // v_min_u32
                k = umx(k, bd[i]);             // v_max_u32
                bd[i] = lo;
            }
        }
        cnt = 0;
        unsigned wb = bd[NSLOT - 1];
        float nw = (wb == SENT) ? INFINITY
                                : __uint_as_float(wb & 0xFFFFF000u) - p2;
        worst_hat = fminf(nw, seed_hat);
    };

    // ---- flat scan, ORIGINAL order, 8-wide (loads batched, 1 ballot/8) ----
    for (int jj = jbeg; jj < jbeg + CHUNK; jj += 8) {
        float4 xv0 = *(const float4*)(tx + jj);
        float4 yv0 = *(const float4*)(ty + jj);
        float4 zv0 = *(const float4*)(tz + jj);
        float4 wv0 = *(const float4*)(tw + jj);
        float4 xv1 = *(const float4*)(tx + jj + 4);
        float4 yv1 = *(const float4*)(ty + jj + 4);
        float4 zv1 = *(const float4*)(tz + jj + 4);
        float4 wv1 = *(const float4*)(tw + jj + 4);
        float xa[8] = {xv0.x, xv0.y, xv0.z, xv0.w, xv1.x, xv1.y, xv1.z, xv1.w};
        float ya[8] = {yv0.x, yv0.y, yv0.z, yv0.w, yv1.x, yv1.y, yv1.z, yv1.w};
        float za[8] = {zv0.x, zv0.y, zv0.z, zv0.w, zv1.x, zv1.y, zv1.z, zv1.w};
        float wa[8] = {wv0.x, wv0.y, wv0.z, wv0.w, wv1.x, wv1.y, wv1.z, wv1.w};
#pragma unroll
        for (int u = 0; u < 8; u++) {
            float dh = fmaf(px, xa[u], fmaf(py, ya[u], fmaf(pz, za[u], wa[u])));
            if (dh < worst_hat) {
                float d = fmaxf(dh + p2, 0.0f);
                scrW[cnt * 64 + lane] = (__float_as_uint(d) & 0xFFFFF000u)
                                        | (unsigned)(jj + u);
                cnt++;
            }
        }
        if (__any(cnt >= 4u)) drain();   // cap-12 safe: <=3 carry + 8/iter
    }
    drain();

    // ---- 8-way merge, two 64-point phases; emits global nbr16 + LDS lnbr ---
    __syncthreads();
    unsigned* mk = (unsigned*)smem;    // words 0..10751
    for (int h = 0; h < 2; h++) {
        if ((pt >> 6) == h) {
            int lpt = pt & 63;
#pragma unroll
            for (int k = 0; k < NSLOT; k++)
                mk[(eighth * 64 + lpt) * MPAD + k] = bd[k];
        }
        __syncthreads();
        if (tid < 64) {
            int p = tid;
            const unsigned* base = &mk[p * MPAD];
            int cur[SPLIT];
#pragma unroll
            for (int q = 0; q < SPLIT; q++) cur[q] = 0;
            int lpt2 = h * 64 + p;
            int gi = b * PP + (int)mOrig[blkInGraph * PTSBLK + lpt2];
#pragma unroll
            for (int t = 0; t < NSLOT; t++) {
                unsigned v[SPLIT];
#pragma unroll
                for (int q = 0; q < SPLIT; q++)
                    v[q] = base[q * 64 * MPAD + cur[q]];
                unsigned m = v[0];
#pragma unroll
                for (int q = 1; q < SPLIT; q++) m = umn(m, v[q]);
                if (t > 0) {
                    int local = (int)(m & 0xFFFu);   // original local idx
                    nbr16[(size_t)gi * KNN + (t - 1)] = (unsigned short)local;
                    lnbr[lpt2 * KNN + (t - 1)] = (unsigned short)local;
                }
#pragma unroll
                for (int q = 0; q < SPLIT; q++) cur[q] += (v[q] == m);
            }
        }
        __syncthreads();
    }

    // ---- re-stage RAW coords in ORIGINAL order (L2-hot) for the eig tail ----
    for (int i = tid; i < PP; i += KTHR) {
        tx[i] = gp[i * 3 + 0];
        ty[i] = gp[i * 3 + 1];
        tz[i] = gp[i * 3 + 2];
    }
    __syncthreads();

    // ---- eig tail: threads 0..127, one point each, all data in LDS ----
    if (tid < PTSBLK) {
        int lp = tid;
        int ng = mOrig[blkInGraph * PTSBLK + lp];   // ORIGINAL local idx
        int n = b * PP + ng;
        float qx = tx[ng], qy = ty[ng], qz = tz[ng];
        const unsigned short* ln = &lnbr[lp * KNN];

        float m00 = 0.f, m01 = 0.f, m02 = 0.f, m11 = 0.f, m12 = 0.f, m22 = 0.f;
#pragma unroll
        for (int k = 0; k < LCOV; k++) {
            int id = ln[k];
            float cx = tx[id] - qx;
            float cy = ty[id] - qy;
            float cz = tz[id] - qz;
            m00 += cx * cx; m01 += cx * cy; m02 += cx * cz;
            m11 += cy * cy; m12 += cy * cz; m22 += cz * cz;
        }
        float M[9] = {m00, m01, m02, m01, m11, m12, m02, m12, m22};

        float v1[3], v2[3], v3[3];
        float l1 = pi3(M, v1);
        float M2[9];
#pragma unroll
        for (int c = 0; c < 3; c++)
#pragma unroll
            for (int d = 0; d < 3; d++)
                M2[c * 3 + d] = M[c * 3 + d] - l1 * v1[c] * v1[d];
        pi3(M2, v2);
        v3[0] = v1[1] * v2[2] - v1[2] * v2[1];
        v3[1] = v1[2] * v2[0] - v1[0] * v2[2];
        v3[2] = v1[0] * v2[1] - v1[1] * v2[0];
        {
            float nrm = sqrtf(v3[0] * v3[0] + v3[1] * v3[1] + v3[2] * v3[2]) + 1e-12f;
            v3[0] /= nrm; v3[1] /= nrm; v3[2] /= nrm;
        }

        float ssum = 0.f, mx = 0.f;
#pragma unroll
        for (int k = 0; k < KNN; k++) {
            int id = ln[k];
            float cx = tx[id] - qx;
            float cy = ty[id] - qy;
            float cz = tz[id] - qz;
            float d0 = cx * v1[0] + cy * v1[1] + cz * v1[2];
            float d1 = cx * v2[0] + cy * v2[1] + cz * v2[2];
            float d2 = cx * v3[0] + cy * v3[1] + cz * v3[2];
            ssum += d2;
            mx = fmaxf(mx, fabsf(d0));
            mx = fmaxf(mx, fabsf(d1));
            mx = fmaxf(mx, fabsf(d2));
        }
        float sgn = (ssum > 0.f) ? 1.f : ((ssum < 0.f) ? -1.f : 0.f);

        float sc = 2.0f / mx;
        float* R = Rbuf + (size_t)n * 12;
        R[0] = v1[0] * sc;  R[1] = v1[1] * sc;  R[2] = v1[2] * sc;
        R[3] = v2[0] * sc;  R[4] = v2[1] * sc;  R[5] = v2[2] * sc;
        float s2 = sgn * sc;
        R[6] = v3[0] * s2;  R[7] = v3[1] * s2;  R[8] = v3[2] * s2;
        R[9] = 0.f; R[10] = 0.f; R[11] = 0.f;

        v3out[n * 3 + 0] = v3[0];
        v3out[n * 3 + 1] = v3[1];
        v3out[n * 3 + 2] = v3[2];
    }
}

// ---------------------------------------------------------------------------
// Kernel 2: spline conv + per-block bn partials (plain stores, R27 path).
// ---------------------------------------------------------------------------
#define NPB 16
#define SPLBLKS (NPTS / NPB)   // 2048
__global__ __launch_bounds__(512) void spline_kernel(
    const float* __restrict__ pos, const unsigned short* __restrict__ nbr16,
    const float* __restrict__ Rbuf, const float* __restrict__ Wsp,
    const float* __restrict__ root, const float* __restrict__ bias,
    float* __restrict__ node, float* __restrict__ sums_part) {
    __shared__ float wbuf[NPB * KNN * 8];    // packed w' per (pt,k,s); reused

    int tid = threadIdx.x;
    if (tid < NPB * KNN) {              // 320 phase-1 threads
        int pt = tid / KNN;
        int k = tid - pt * KNN;
        int n = blockIdx.x * NPB + pt;
        const float4* Rv = (const float4*)(Rbuf + (size_t)n * 12);
        float4 r0 = Rv[0], r1 = Rv[1], r2 = Rv[2];
        float px = pos[n * 3 + 0], py = pos[n * 3 + 1], pz = pos[n * 3 + 2];
        int id = (n & ~(PP - 1)) | (int)nbr16[(size_t)n * KNN + k];
        float cxx = pos[id * 3 + 0] - px;
        float cyy = pos[id * 3 + 1] - py;
        float czz = pos[id * 3 + 2] - pz;
        float v0 = fmaf(cxx, r0.x, fmaf(cyy, r0.y, fmaf(czz, r0.z, 2.0f)));
        float v1 = fmaf(cxx, r0.w, fmaf(cyy, r1.x, fmaf(czz, r1.y, 2.0f)));
        float v2 = fmaf(cxx, r1.z, fmaf(cyy, r1.w, fmaf(czz, r2.x, 2.0f)));
        float f0 = floorf(v0), f1 = floorf(v1), f2 = floorf(v2);
        float fr0 = v0 - f0, fr1 = v1 - f1, fr2 = v2 - f2;
        int fi0 = (int)f0, fi1 = (int)f1, fi2 = (int)f2;
        float* wdst = &wbuf[(pt * KNN + k) * 8];
#pragma unroll
        for (int s = 0; s < 8; s++) {
            int b0 = (s >> 2) & 1, b1 = (s >> 1) & 1, b2s = s & 1;
            int i0 = min(max(fi0 + b0, 0), KS - 1);
            int i1 = min(max(fi1 + b1, 0), KS - 1);
            int i2 = min(max(fi2 + b2s, 0), KS - 1);
            float w = (b0 ? fr0 : 1.f - fr0) * (b1 ? fr1 : 1.f - fr1) *
                      (b2s ? fr2 : 1.f - fr2);
            unsigned flat = (unsigned)((i0 * KS + i1) * KS + i2);
            wdst[s] = __uint_as_float((__float_as_uint(w) & ~127u) | flat);
        }
    }
    __syncthreads();

    // phase 2: thread = (pt, f); Wsp read direct (L1-resident, coalesced)
    int pt = tid >> 5;
    int f = tid & 31;
    const float* wrow = &wbuf[pt * (KNN * 8)];
    float acc = 0.f;
#pragma unroll
    for (int k = 0; k < KNN; k++) {
        float4 wa = *(const float4*)&wrow[k * 8];
        float4 wb = *(const float4*)&wrow[k * 8 + 4];
        float wv[8] = {wa.x, wa.y, wa.z, wa.w, wb.x, wb.y, wb.z, wb.w};
#pragma unroll
        for (int s = 0; s < 8; s++) {
            unsigned u = __float_as_uint(wv[s]) & 127u;
            acc = fmaf(wv[s], Wsp[u * FF + f], acc);
        }
    }
    int n = blockIdx.x * NPB + pt;
    float val = acc * (1.0f / KNN) + root[f] + bias[f];
    node[(size_t)n * FF + f] = val;

    // ---- per-block bn partial (plain stores; kernel boundary = sync) ----
    __syncthreads();                 // wbuf reads done; safe to reuse
    wbuf[tid] = val;
    wbuf[512 + tid] = val * val;
    __syncthreads();
    if (tid < 64) {
        int ff = tid & 31;
        int off = (tid >> 5) * 512;  // 0 = sum, 512 = sumsq
        float s = 0.f;
#pragma unroll
        for (int p = 0; p < NPB; p++) s += wbuf[off + p * 32 + ff];
        sums_part[(size_t)blockIdx.x * 64 + tid] = s;
    }
}

// ---------------------------------------------------------------------------
// Kernel 2b: single-pass stats reduce — 64 blocks, one column each.
// sums_accum[c] = sum over 2048 rows of sums_part[r][c].
// ---------------------------------------------------------------------------
__global__ __launch_bounds__(256) void stats_kernel(
    const float* __restrict__ sums_part, float* __restrict__ sums_accum) {
    int c = blockIdx.x;              // 0..63
    __shared__ float red[256];
    float s = 0.f;
    for (int r = threadIdx.x; r < SPLBLKS; r += 256)
        s += sums_part[(size_t)r * 64 + c];
    red[threadIdx.x] = s;
    __syncthreads();
    for (int off = 128; off > 0; off >>= 1) {
        if (threadIdx.x < off) red[threadIdx.x] += red[threadIdx.x + off];
        __syncthreads();
    }
    if (threadIdx.x == 0) sums_accum[c] = red[0];
}

// ---------------------------------------------------------------------------
// Kernel 3: BN apply + sigmoid + reduce to ys partials (YSPLIT=32: 768
// blocks = 3 waves/SIMD; 16 elements/thread = 5 triples + 1).
// ---------------------------------------------------------------------------
#define YSPLIT 32
#define YCHUNK (GROUPLEN / YSPLIT)   // 4096
__global__ __launch_bounds__(256) void ys_kernel(
    const float* __restrict__ node, const float* __restrict__ v3,
    const float* __restrict__ sums_accum, const float* __restrict__ gamma,
    const float* __restrict__ beta, float* __restrict__ ys_part) {
    __shared__ float sa[FF], sb[FF];
    if (threadIdx.x < FF) {
        int f = threadIdx.x;
        float mu = sums_accum[f] * (1.0f / NPTS);
        float var = sums_accum[FF + f] * (1.0f / NPTS) - mu * mu;
        float inv = 1.0f / sqrtf(var + 1e-5f);
        sa[f] = gamma[f] * inv;
        sb[f] = beta[f] - gamma[f] * inv * mu;
    }
    __syncthreads();

    int g = blockIdx.x >> 5;
    int sub = blockIdx.x & 31;
    int t0 = g * GROUPLEN + sub * YCHUNK + threadIdx.x;
    int n = t0 / 96;
    int r0 = t0 - n * 96;
    int rj[3], fj[3], cj[3], dj[3];
    rj[0] = r0;
    rj[1] = (r0 + 64) % 96;
    rj[2] = (r0 + 32) % 96;
#pragma unroll
    for (int j = 0; j < 3; j++) {
        fj[j] = rj[j] / 3;
        cj[j] = rj[j] - fj[j] * 3;
        dj[j] = (rj[j] >= 32) ? 3 : 2;
    }
    float Sa0 = sa[fj[0]], Sb0 = sb[fj[0]];
    float Sa1 = sa[fj[1]], Sb1 = sb[fj[1]];
    float Sa2 = sa[fj[2]], Sb2 = sb[fj[2]];
    int nf = n * FF;
    int n3 = n * 3;

    float acc = 0.f;
#pragma unroll 1
    for (int tr = 0; tr < 5; tr++) {
        {
            float xb = fmaf(Sa0, node[nf + fj[0]], Sb0);
            float val = xb * v3[n3 + cj[0]];
            acc += 1.0f / (1.0f + __expf(-val));
            nf += dj[0] * FF; n3 += dj[0] * 3;
        }
        {
            float xb = fmaf(Sa1, node[nf + fj[1]], Sb1);
            float val = xb * v3[n3 + cj[1]];
            acc += 1.0f / (1.0f + __expf(-val));
            nf += dj[1] * FF; n3 += dj[1] * 3;
        }
        {
            float xb = fmaf(Sa2, node[nf + fj[2]], Sb2);
            float val = xb * v3[n3 + cj[2]];
            acc += 1.0f / (1.0f + __expf(-val));
            nf += dj[2] * FF; n3 += dj[2] * 3;
        }
    }
    {
        float xb = fmaf(Sa0, node[nf + fj[0]], Sb0);
        float val = xb * v3[n3 + cj[0]];
        acc += 1.0f / (1.0f + __expf(-val));
    }

    __shared__ float red[256];
    red[threadIdx.x] = acc;
    __syncthreads();
    if (threadIdx.x < FF) {
        float s = 0.f;
        for (int t = threadIdx.x; t < 256; t += FF) s += red[t];
        ys_part[(sub * NGROUP + g) * FF + threadIdx.x] = s * (1.0f / PP);
    }
}

// ---------------------------------------------------------------------------
// Kernel 4: MLP head; sums the 32 ys partials while loading syr.
// ---------------------------------------------------------------------------
__global__ __launch_bounds__(256) void head_kernel(
    const float* __restrict__ ys_part, const float* __restrict__ W1,
    const float* __restrict__ b1, const float* __restrict__ W2,
    const float* __restrict__ b2, float* __restrict__ out) {
    int g = blockIdx.x;
    __shared__ float syr[FF];
    __shared__ float h[256];
    __shared__ float logits[NCLS];
    __shared__ float mstat[2];
    if (threadIdx.x < FF) {
        float s = 0.f;
#pragma unroll
        for (int sub = 0; sub < YSPLIT; sub++)
            s += ys_part[(sub * NGROUP + g) * FF + threadIdx.x];
        syr[threadIdx.x] = s;
    }
    __syncthreads();
    int j = threadIdx.x;
    float acc = b1[j];
#pragma unroll
    for (int f = 0; f < FF; f++) acc += syr[f] * W1[f * 256 + j];
    h[j] = acc > 0.f ? acc : expm1f(acc);
    __syncthreads();
    if (j < NCLS) {
        float l = b2[j];
        for (int q = 0; q < 256; q++) l += h[q] * W2[q * NCLS + j];
        logits[j] = l;
    }
    __syncthreads();
    if (j == 0) {
        float m = -INFINITY;
        for (int o = 0; o < NCLS; o++) m = fmaxf(m, logits[o]);
        float s = 0.f;
        for (int o = 0; o < NCLS; o++) s += expf(logits[o] - m);
        mstat[0] = m;
        mstat[1] = logf(s);
    }
    __syncthreads();
    if (j < NCLS) out[g * NCLS + j] = logits[j] - mstat[0] - mstat[1];
}

// ---------------------------------------------------------------------------
extern "C" void kernel_launch(void* const* d_in, const int* in_sizes, int n_in,
                              void* d_out, int out_size, void* d_ws, size_t ws_size,
                              hipStream_t stream) {
    const float* pos   = (const float*)d_in[0];
    const float* Wsp   = (const float*)d_in[1];
    const float* root  = (const float*)d_in[2];
    const float* bias  = (const float*)d_in[3];
    const float* gamma = (const float*)d_in[4];
    const float* beta  = (const float*)d_in[5];
    const float* W1    = (const float*)d_in[6];
    const float* b1    = (const float*)d_in[7];
    const float* W2    = (const float*)d_in[8];
    const float* b2    = (const float*)d_in[9];
    float* out = (float*)d_out;

    char* ws = (char*)d_ws;
    unsigned short* nbr16 = (unsigned short*)(ws);     // 32768*20*2 = 1310720
    float* sums_part = (float*)(ws + 1310720);         // 2048*64*4  = 524288
    float* ys_part   = (float*)(ws + 1835008);         // 32*24*32*4 = 98304
    float* sums_accum = (float*)(ws + 1933312);        // 64*4 = 256
    float* node = (float*)(ws + 2621440);              // 32768*32*4 = 4194304
    float* v3   = (float*)(ws + 6815744);              // 32768*3*4  = 393216
    float* Rbuf = (float*)(ws + 7212288);              // 32768*12*4 = 1572864

    knn_kernel<<<256, KTHR, 0, stream>>>(pos, nbr16, Rbuf, v3);
    spline_kernel<<<SPLBLKS, 512, 0, stream>>>(pos, nbr16, Rbuf, Wsp, root,
                                               bias, node, sums_part);
    stats_kernel<<<64, 256, 0, stream>>>(sums_part, sums_accum);
    ys_kernel<<<NGROUP * YSPLIT, 256, 0, stream>>>(node, v3, sums_accum, gamma,
                                                   beta, ys_part);
    head_kernel<<<NGROUP, 256, 0, stream>>>(ys_part, W1, b1, W2, b2, out);
}

// Round 16
// 187.556 us; speedup vs baseline: 1.1680x; 1.0280x over previous
//
#include <hip/hip_runtime.h>
#include <hip/hip_bf16.h>
#include <math.h>

// Problem constants
#define BGR 8        // graphs
#define PP 4096      // points per graph
#define NPTS 32768   // B*P
#define KNN 20
#define LCOV 10
#define FF 32
#define KS 5
#define NCLS 40
#define NGROUP 24    // 3*B, rows of ys
#define GROUPLEN 131072  // P*F flat elements per group

// KNN tiling: 256 blocks x 1024 threads; thread = (eighth 0..7, pt 0..127)
#define SPLIT 8
#define CHUNK (PP / SPLIT)        // 512 candidates per thread
#define PTSBLK 128                // points per block
#define KTHR 1024
#define NSLOT (KNN + 1)           // 21-slot network (self-point absorbable)
#define MPAD NSLOT                // merge-list stride 21: gcd(21,32)=1
#define SENT 0xFFFFFFFFu
#define SCELLS 4096
#define SCAP 12                   // LDS scratch slots per lane
#define KBLKS 256                 // knn blocks = BN-partial rows

// ---------------------------------------------------------------------------
// R30 vs R29 (192.8us best; knn 80.8): R29's null (removing the 192x stats
// reduce didn't move non-knn) recalibrates the model — that reduce was
// L2-served (~3us). Real non-knn kernel time ~25us (spline 7-12, ys 3,
// stats 1, head 5); the remaining ~85us of the 112 is fixed harness/graph
// overhead (reset memsets in the timed region) — untouchable from kernels.
// Last controllable lever: FUSE SPLINE INTO KNN's TAIL (all inputs already
// in LDS: raw coords, lnbr, eigvecs/sc/sgn in regs):
//   - eig tail stores scaled R rows to samp overlay (no Rbuf global);
//   - w' phase: 2560 (pt,k) pairs -> packed w' into dead scr overlay (40KB);
//   - node phase: thread=(pt,f) x4, 20k x 8s fma vs L1-resident Wsp,
//     writes node + BN partials -> sums_part[256][64];
//   - arithmetic replicated op-for-op => bit-identical node.
// Removes: spline launch, Rbuf (3MB traffic), pos/nbr16 re-reads, nbr16
// writes. stats_kernel reduces 256 rows. ys/head byte-identical (R29).
// Predicted: knn ~88-95, WRITE ~9.5MB, spline row gone, total ~180-190.
// Pre-committed: total >= 192 => fusion neutral => declare plateau next.
// ---------------------------------------------------------------------------
__device__ inline unsigned umn(unsigned a, unsigned b) { return a < b ? a : b; }
__device__ inline unsigned umx(unsigned a, unsigned b) { return a > b ? a : b; }

__device__ inline void mat3vec(const float M[9], const float v[3], float w[3]) {
    w[0] = M[0] * v[0] + M[1] * v[1] + M[2] * v[2];
    w[1] = M[3] * v[0] + M[4] * v[1] + M[5] * v[2];
    w[2] = M[6] * v[0] + M[7] * v[1] + M[8] * v[2];
}

__device__ inline float pi3(const float M[9], float v[3]) {
    v[0] = v[1] = v[2] = 0.57735026918962576f;  // 3^-0.5 as f32
#pragma unroll
    for (int it = 0; it < 5; ++it) {
        float w[3];
        mat3vec(M, v, w);
        float nrm = sqrtf(w[0] * w[0] + w[1] * w[1] + w[2] * w[2]) + 1e-12f;
        v[0] = w[0] / nrm;
        v[1] = w[1] / nrm;
        v[2] = w[2] / nrm;
    }
    float w[3];
    mat3vec(M, v, w);
    return v[0] * w[0] + v[1] * w[1] + v[2] * w[2];
}

__global__ __launch_bounds__(KTHR, 4) void knn_kernel(
    const float* __restrict__ pos, const float* __restrict__ Wsp,
    const float* __restrict__ root, const float* __restrict__ bias,
    float* __restrict__ node, float* __restrict__ sums_part,
    float* __restrict__ v3out) {
    __shared__ float smem[4 * PP];           // 64 KB arena
    __shared__ unsigned short mOrig[PP];     // Morton slot -> original local idx
    __shared__ unsigned samp[PTSBLK * 24];   // 12 KB: seed keys | R rows | BN red
    __shared__ float Tseed[PTSBLK];
    __shared__ unsigned scr[KTHR / 64][SCAP][64];  // 48 KB: accepts | w' overlay
    float* tx = smem;                // scan: -2x (ORIGINAL order) | merge: mk
    float* ty = smem + PP;
    float* tz = smem + 2 * PP;
    float* tw = smem + 3 * PP;       // |q|^2 (dead after scan)
    unsigned short* lnbr = (unsigned short*)(smem + 3 * PP + 2816);

    int b = blockIdx.x >> 5;          // 32 blocks per graph
    int blkInGraph = blockIdx.x & 31;
    const float* gp = pos + (size_t)b * PP * 3;
    int tid = threadIdx.x;
    int lane = tid & 63;
    int wid = tid >> 6;

    // ---- Phase A: Morton-cell counting sort (per-block, overlays arena) ----
    {
        unsigned* cnt = (unsigned*)smem;                         // words 0..4095
        unsigned short* cellOf = (unsigned short*)(smem + 4096); // words 4096..6143
        unsigned* tsum = (unsigned*)(smem + 6144);               // words 6144..7167
        for (int i = tid; i < SCELLS; i += KTHR) cnt[i] = 0u;
        __syncthreads();
        for (int i = tid; i < PP; i += KTHR) {
            float x = gp[i * 3 + 0];
            float y = gp[i * 3 + 1];
            float z = gp[i * 3 + 2];
            int cx = min(max((int)floorf((x + 4.0f) * 2.0f), 0), 15);
            int cy = min(max((int)floorf((y + 4.0f) * 2.0f), 0), 15);
            int cz = min(max((int)floorf((z + 4.0f) * 2.0f), 0), 15);
            unsigned m = 0;
#pragma unroll
            for (int bb = 0; bb < 4; ++bb)
                m |= (((unsigned)(cx >> bb) & 1u) << (3 * bb + 2)) |
                     (((unsigned)(cy >> bb) & 1u) << (3 * bb + 1)) |
                     (((unsigned)(cz >> bb) & 1u) << (3 * bb + 0));
            cellOf[i] = (unsigned short)m;
            atomicAdd(&cnt[m], 1u);
        }
        __syncthreads();
        unsigned c0 = cnt[4 * tid + 0];
        unsigned c1 = cnt[4 * tid + 1];
        unsigned c2 = cnt[4 * tid + 2];
        unsigned c3 = cnt[4 * tid + 3];
        unsigned local = c0 + c1 + c2 + c3;
        tsum[tid] = local;
        __syncthreads();
        for (int off = 1; off < 1024; off <<= 1) {
            unsigned v = (tid >= off) ? tsum[tid - off] : 0u;
            __syncthreads();
            tsum[tid] += v;
            __syncthreads();
        }
        unsigned base = tsum[tid] - local;   // exclusive prefix
        cnt[4 * tid + 0] = base;
        cnt[4 * tid + 1] = base + c0;
        cnt[4 * tid + 2] = base + c0 + c1;
        cnt[4 * tid + 3] = base + c0 + c1 + c2;
        __syncthreads();
        for (int i = tid; i < PP; i += KTHR) {
            unsigned dst = atomicAdd(&cnt[cellOf[i]], 1u);
            mOrig[dst] = (unsigned short)i;
        }
    }
    __syncthreads();

    // ---- Phase B: stage scan arrays in ORIGINAL order ----
    for (int i = tid; i < PP; i += KTHR) {
        float x = gp[i * 3 + 0];
        float y = gp[i * 3 + 1];
        float z = gp[i * 3 + 2];
        tx[i] = -2.0f * x;
        ty[i] = -2.0f * y;
        tz[i] = -2.0f * z;
        tw[i] = x * x + y * y + z * z;
    }
    __syncthreads();

    int eighth = tid >> 7;                // 0..7 (wave-uniform)
    int pt = tid & (PTSBLK - 1);          // 0..127
    int qSlot = blkInGraph * PTSBLK + pt; // query's Morton slot in graph
    int li = mOrig[qSlot];                // ORIGINAL local point index
    float px = -0.5f * tx[li];
    float py = -0.5f * ty[li];
    float pz = -0.5f * tz[li];
    float p2 = tw[li];
    int jbeg = eighth * CHUNK;

    // ---- seed: top-3 of 32 chunks x 4 consecutive slots (float4 loads) ----
    {
        unsigned s0 = SENT, s1 = SENT, s2 = SENT;
#pragma unroll 4
        for (int c = 0; c < 32; ++c) {
            int base = jbeg + c * 16;     // 4-aligned; max base+3 = jbeg+499
            float4 xv = *(const float4*)(tx + base);
            float4 yv = *(const float4*)(ty + base);
            float4 zv = *(const float4*)(tz + base);
            float4 wv = *(const float4*)(tw + base);
            float xa[4] = {xv.x, xv.y, xv.z, xv.w};
            float ya[4] = {yv.x, yv.y, yv.z, yv.w};
            float za[4] = {zv.x, zv.y, zv.z, zv.w};
            float wa[4] = {wv.x, wv.y, wv.z, wv.w};
#pragma unroll
            for (int u = 0; u < 4; ++u) {
                float dh = fmaf(px, xa[u], fmaf(py, ya[u], fmaf(pz, za[u], wa[u])));
                float d = fmaxf(dh + p2, 0.0f);
                unsigned key = (__float_as_uint(d) & 0xFFFFF000u)
                               | (unsigned)(base + u);
                if (base + u == li) key = SENT;   // self excluded
                unsigned t0 = umn(key, s0); key = umx(key, s0); s0 = t0;
                t0 = umn(key, s1); key = umx(key, s1); s1 = t0;
                s2 = umn(key, s2);
            }
        }
        unsigned* sdst = &samp[pt * 24 + eighth * 3];
        sdst[0] = s0; sdst[1] = s1; sdst[2] = s2;
    }
    __syncthreads();
    if (tid < PTSBLK) {
        // T = 21st smallest of 24 = 4th largest; +2 trunc-ulps headroom.
        unsigned g0 = 0, g1 = 0, g2 = 0, g3 = 0;
        const unsigned* ss = &samp[tid * 24];
#pragma unroll
        for (int i = 0; i < 24; ++i) {
            unsigned k = ss[i], a;
            a = umx(k, g0); k = umn(k, g0); g0 = a;
            a = umx(k, g1); k = umn(k, g1); g1 = a;
            a = umx(k, g2); k = umn(k, g2); g2 = a;
            g3 = umx(k, g3);
        }
        Tseed[tid] = __uint_as_float((g3 & 0xFFFFF000u) + 0x2000u);
    }
    __syncthreads();
    float seed_hat = Tseed[pt] - p2;

    unsigned bd[NSLOT];
#pragma unroll
    for (int k = 0; k < NSLOT; k++) bd[k] = SENT;
    float worst_hat = seed_hat;

    unsigned* scrW = &scr[wid][0][0];
    unsigned cnt = 0;

    auto drain = [&]() {
#pragma unroll
        for (int s = 0; s < SCAP; ++s) {
            if (!__any((int)cnt > s)) break;   // monotone fill 0..cnt-1
            unsigned k = (s < (int)cnt) ? scrW[s * 64 + lane] : SENT;
#pragma unroll
            for (int i = 0; i < NSLOT; i++) {
                unsigned lo = umn(k, bd[i]);   // v_min_u32
                k = umx(k, bd[i]);             // v_max_u32
                bd[i] = lo;
            }
        }
        cnt = 0;
        unsigned wb = bd[NSLOT - 1];
        float nw = (wb == SENT) ? INFINITY
                                : __uint_as_float(wb & 0xFFFFF000u) - p2;
        worst_hat = fminf(nw, seed_hat);
    };

    // ---- flat scan, ORIGINAL order, 8-wide (loads batched, 1 ballot/8) ----
    for (int jj = jbeg; jj < jbeg + CHUNK; jj += 8) {
        float4 xv0 = *(const float4*)(tx + jj);
        float4 yv0 = *(const float4*)(ty + jj);
        float4 zv0 = *(const float4*)(tz + jj);
        float4 wv0 = *(const float4*)(tw + jj);
        float4 xv1 = *(const float4*)(tx + jj + 4);
        float4 yv1 = *(const float4*)(ty + jj + 4);
        float4 zv1 = *(const float4*)(tz + jj + 4);
        float4 wv1 = *(const float4*)(tw + jj + 4);
        float xa[8] = {xv0.x, xv0.y, xv0.z, xv0.w, xv1.x, xv1.y, xv1.z, xv1.w};
        float ya[8] = {yv0.x, yv0.y, yv0.z, yv0.w, yv1.x, yv1.y, yv1.z, yv1.w};
        float za[8] = {zv0.x, zv0.y, zv0.z, zv0.w, zv1.x, zv1.y, zv1.z, zv1.w};
        float wa[8] = {wv0.x, wv0.y, wv0.z, wv0.w, wv1.x, wv1.y, wv1.z, wv1.w};
#pragma unroll
        for (int u = 0; u < 8; u++) {
            float dh = fmaf(px, xa[u], fmaf(py, ya[u], fmaf(pz, za[u], wa[u])));
            if (dh < worst_hat) {
                float d = fmaxf(dh + p2, 0.0f);
                scrW[cnt * 64 + lane] = (__float_as_uint(d) & 0xFFFFF000u)
                                        | (unsigned)(jj + u);
                cnt++;
            }
        }
        if (__any(cnt >= 4u)) drain();   // cap-12 safe: <=3 carry + 8/iter
    }
    drain();

    // ---- 8-way merge, two 64-point phases; emits LDS lnbr only ----
    __syncthreads();
    unsigned* mk = (unsigned*)smem;    // words 0..10751
    for (int h = 0; h < 2; h++) {
        if ((pt >> 6) == h) {
            int lpt = pt & 63;
#pragma unroll
            for (int k = 0; k < NSLOT; k++)
                mk[(eighth * 64 + lpt) * MPAD + k] = bd[k];
        }
        __syncthreads();
        if (tid < 64) {
            int p = tid;
            const unsigned* base = &mk[p * MPAD];
            int cur[SPLIT];
#pragma unroll
            for (int q = 0; q < SPLIT; q++) cur[q] = 0;
            int lpt2 = h * 64 + p;
#pragma unroll
            for (int t = 0; t < NSLOT; t++) {
                unsigned v[SPLIT];
#pragma unroll
                for (int q = 0; q < SPLIT; q++)
                    v[q] = base[q * 64 * MPAD + cur[q]];
                unsigned m = v[0];
#pragma unroll
                for (int q = 1; q < SPLIT; q++) m = umn(m, v[q]);
                if (t > 0) {
                    lnbr[lpt2 * KNN + (t - 1)] = (unsigned short)(m & 0xFFFu);
                }
#pragma unroll
                for (int q = 0; q < SPLIT; q++) cur[q] += (v[q] == m);
            }
        }
        __syncthreads();
    }

    // ---- re-stage RAW coords in ORIGINAL order (L2-hot) for the tail ----
    for (int i = tid; i < PP; i += KTHR) {
        tx[i] = gp[i * 3 + 0];
        ty[i] = gp[i * 3 + 1];
        tz[i] = gp[i * 3 + 2];
    }
    __syncthreads();

    // ---- eig tail: threads 0..127; R rows -> samp overlay (no Rbuf) ----
    if (tid < PTSBLK) {
        int lp = tid;
        int ng = mOrig[blkInGraph * PTSBLK + lp];   // ORIGINAL local idx
        int n = b * PP + ng;
        float qx = tx[ng], qy = ty[ng], qz = tz[ng];
        const unsigned short* ln = &lnbr[lp * KNN];

        float m00 = 0.f, m01 = 0.f, m02 = 0.f, m11 = 0.f, m12 = 0.f, m22 = 0.f;
#pragma unroll
        for (int k = 0; k < LCOV; k++) {
            int id = ln[k];
            float cx = tx[id] - qx;
            float cy = ty[id] - qy;
            float cz = tz[id] - qz;
            m00 += cx * cx; m01 += cx * cy; m02 += cx * cz;
            m11 += cy * cy; m12 += cy * cz; m22 += cz * cz;
        }
        float M[9] = {m00, m01, m02, m01, m11, m12, m02, m12, m22};

        float v1[3], v2[3], v3[3];
        float l1 = pi3(M, v1);
        float M2[9];
#pragma unroll
        for (int c = 0; c < 3; c++)
#pragma unroll
            for (int d = 0; d < 3; d++)
                M2[c * 3 + d] = M[c * 3 + d] - l1 * v1[c] * v1[d];
        pi3(M2, v2);
        v3[0] = v1[1] * v2[2] - v1[2] * v2[1];
        v3[1] = v1[2] * v2[0] - v1[0] * v2[2];
        v3[2] = v1[0] * v2[1] - v1[1] * v2[0];
        {
            float nrm = sqrtf(v3[0] * v3[0] + v3[1] * v3[1] + v3[2] * v3[2]) + 1e-12f;
            v3[0] /= nrm; v3[1] /= nrm; v3[2] /= nrm;
        }

        float ssum = 0.f, mx = 0.f;
#pragma unroll
        for (int k = 0; k < KNN; k++) {
            int id = ln[k];
            float cx = tx[id] - qx;
            float cy = ty[id] - qy;
            float cz = tz[id] - qz;
            float d0 = cx * v1[0] + cy * v1[1] + cz * v1[2];
            float d1 = cx * v2[0] + cy * v2[1] + cz * v2[2];
            float d2 = cx * v3[0] + cy * v3[1] + cz * v3[2];
            ssum += d2;
            mx = fmaxf(mx, fabsf(d0));
            mx = fmaxf(mx, fabsf(d1));
            mx = fmaxf(mx, fabsf(d2));
        }
        float sgn = (ssum > 0.f) ? 1.f : ((ssum < 0.f) ? -1.f : 0.f);

        float sc = 2.0f / mx;
        float* rrow = (float*)samp + lp * 12;
        rrow[0] = v1[0] * sc;  rrow[1] = v1[1] * sc;  rrow[2] = v1[2] * sc;
        rrow[3] = v2[0] * sc;  rrow[4] = v2[1] * sc;  rrow[5] = v2[2] * sc;
        float s2g = sgn * sc;
        rrow[6] = v3[0] * s2g; rrow[7] = v3[1] * s2g; rrow[8] = v3[2] * s2g;

        v3out[n * 3 + 0] = v3[0];
        v3out[n * 3 + 1] = v3[1];
        v3out[n * 3 + 2] = v3[2];
    }
    __syncthreads();

    // ---- fused spline, phase 1: packed w' for 128 pts x 20 k -> scr ----
    {
        float* wb = (float*)scr;                 // 40KB of 48KB (scan is done)
        const float* sampF = (const float*)samp; // R rows per pt
        for (int i = tid; i < PTSBLK * KNN; i += KTHR) {
            int lp = i / KNN;
            int k = i - lp * KNN;
            int ng = mOrig[blkInGraph * PTSBLK + lp];
            float qx = tx[ng], qy = ty[ng], qz = tz[ng];
            int id = lnbr[lp * KNN + k];
            float cxx = tx[id] - qx;
            float cyy = ty[id] - qy;
            float czz = tz[id] - qz;
            const float* r = &sampF[lp * 12];
            float v0 = fmaf(cxx, r[0], fmaf(cyy, r[1], fmaf(czz, r[2], 2.0f)));
            float v1 = fmaf(cxx, r[3], fmaf(cyy, r[4], fmaf(czz, r[5], 2.0f)));
            float v2 = fmaf(cxx, r[6], fmaf(cyy, r[7], fmaf(czz, r[8], 2.0f)));
            float f0 = floorf(v0), f1 = floorf(v1), f2 = floorf(v2);
            float fr0 = v0 - f0, fr1 = v1 - f1, fr2 = v2 - f2;
            int fi0 = (int)f0, fi1 = (int)f1, fi2 = (int)f2;
            float* wdst = &wb[i * 8];
#pragma unroll
            for (int s = 0; s < 8; s++) {
                int b0 = (s >> 2) & 1, b1 = (s >> 1) & 1, b2s = s & 1;
                int i0 = min(max(fi0 + b0, 0), KS - 1);
                int i1 = min(max(fi1 + b1, 0), KS - 1);
                int i2 = min(max(fi2 + b2s, 0), KS - 1);
                float w = (b0 ? fr0 : 1.f - fr0) * (b1 ? fr1 : 1.f - fr1) *
                          (b2s ? fr2 : 1.f - fr2);
                unsigned flat = (unsigned)((i0 * KS + i1) * KS + i2);
                wdst[s] = __uint_as_float((__float_as_uint(w) & ~127u) | flat);
            }
        }
    }
    __syncthreads();

    // ---- fused spline, phase 2: node + BN partials (thread=(pt,f) x4) ----
    {
        const float* wb = (const float*)scr;
        float bn1 = 0.f, bn2 = 0.f;
        int f = tid & 31;
#pragma unroll
        for (int it = 0; it < 4; ++it) {
            int lp = (tid >> 5) + 32 * it;     // 0..127
            const float* wrow = &wb[(lp * KNN) * 8];
            float acc = 0.f;
#pragma unroll
            for (int k = 0; k < KNN; k++) {
                float4 wa = *(const float4*)&wrow[k * 8];
                float4 wb4 = *(const float4*)&wrow[k * 8 + 4];
                float wv[8] = {wa.x, wa.y, wa.z, wa.w, wb4.x, wb4.y, wb4.z, wb4.w};
#pragma unroll
                for (int s = 0; s < 8; s++) {
                    unsigned u = __float_as_uint(wv[s]) & 127u;
                    acc = fmaf(wv[s], Wsp[u * FF + f], acc);
                }
            }
            float val = acc * (1.0f / KNN) + root[f] + bias[f];
            int ng = mOrig[blkInGraph * PTSBLK + lp];
            node[((size_t)b * PP + ng) * FF + f] = val;
            bn1 += val;
            bn2 += val * val;
        }
        float* redF = (float*)samp;            // 8KB of 12KB (R rows dead)
        redF[tid] = bn1;
        redF[1024 + tid] = bn2;
        __syncthreads();
        if (tid < 64) {
            int ff = tid & 31;
            int off = (tid >> 5) * 1024;       // 0 = sum, 1024 = sumsq
            float s = 0.f;
#pragma unroll
            for (int g = 0; g < 32; ++g) s += redF[off + (g << 5) + ff];
            sums_part[(size_t)blockIdx.x * 64 + tid] = s;
        }
    }
}

// ---------------------------------------------------------------------------
// Kernel 2b: single-pass stats reduce — 64 blocks, one column each.
// sums_accum[c] = sum over KBLKS rows of sums_part[r][c].
// ---------------------------------------------------------------------------
__global__ __launch_bounds__(256) void stats_kernel(
    const float* __restrict__ sums_part, float* __restrict__ sums_accum) {
    int c = blockIdx.x;              // 0..63
    __shared__ float red[256];
    float s = 0.f;
    for (int r = threadIdx.x; r < KBLKS; r += 256)
        s += sums_part[(size_t)r * 64 + c];
    red[threadIdx.x] = s;
    __syncthreads();
    for (int off = 128; off > 0; off >>= 1) {
        if (threadIdx.x < off) red[threadIdx.x] += red[threadIdx.x + off];
        __syncthreads();
    }
    if (threadIdx.x == 0) sums_accum[c] = red[0];
}

// ---------------------------------------------------------------------------
// Kernel 3: BN apply + sigmoid + reduce to ys partials (YSPLIT=32: 768
// blocks = 3 waves/SIMD; 16 elements/thread = 5 triples + 1).
// ---------------------------------------------------------------------------
#define YSPLIT 32
#define YCHUNK (GROUPLEN / YSPLIT)   // 4096
__global__ __launch_bounds__(256) void ys_kernel(
    const float* __restrict__ node, const float* __restrict__ v3,
    const float* __restrict__ sums_accum, const float* __restrict__ gamma,
    const float* __restrict__ beta, float* __restrict__ ys_part) {
    __shared__ float sa[FF], sb[FF];
    if (threadIdx.x < FF) {
        int f = threadIdx.x;
        float mu = sums_accum[f] * (1.0f / NPTS);
        float var = sums_accum[FF + f] * (1.0f / NPTS) - mu * mu;
        float inv = 1.0f / sqrtf(var + 1e-5f);
        sa[f] = gamma[f] * inv;
        sb[f] = beta[f] - gamma[f] * inv * mu;
    }
    __syncthreads();

    int g = blockIdx.x >> 5;
    int sub = blockIdx.x & 31;
    int t0 = g * GROUPLEN + sub * YCHUNK + threadIdx.x;
    int n = t0 / 96;
    int r0 = t0 - n * 96;
    int rj[3], fj[3], cj[3], dj[3];
    rj[0] = r0;
    rj[1] = (r0 + 64) % 96;
    rj[2] = (r0 + 32) % 96;
#pragma unroll
    for (int j = 0; j < 3; j++) {
        fj[j] = rj[j] / 3;
        cj[j] = rj[j] - fj[j] * 3;
        dj[j] = (rj[j] >= 32) ? 3 : 2;
    }
    float Sa0 = sa[fj[0]], Sb0 = sb[fj[0]];
    float Sa1 = sa[fj[1]], Sb1 = sb[fj[1]];
    float Sa2 = sa[fj[2]], Sb2 = sb[fj[2]];
    int nf = n * FF;
    int n3 = n * 3;

    float acc = 0.f;
#pragma unroll 1
    for (int tr = 0; tr < 5; tr++) {
        {
            float xb = fmaf(Sa0, node[nf + fj[0]], Sb0);
            float val = xb * v3[n3 + cj[0]];
            acc += 1.0f / (1.0f + __expf(-val));
            nf += dj[0] * FF; n3 += dj[0] * 3;
        }
        {
            float xb = fmaf(Sa1, node[nf + fj[1]], Sb1);
            float val = xb * v3[n3 + cj[1]];
            acc += 1.0f / (1.0f + __expf(-val));
            nf += dj[1] * FF; n3 += dj[1] * 3;
        }
        {
            float xb = fmaf(Sa2, node[nf + fj[2]], Sb2);
            float val = xb * v3[n3 + cj[2]];
            acc += 1.0f / (1.0f + __expf(-val));
            nf += dj[2] * FF; n3 += dj[2] * 3;
        }
    }
    {
        float xb = fmaf(Sa0, node[nf + fj[0]], Sb0);
        float val = xb * v3[n3 + cj[0]];
        acc += 1.0f / (1.0f + __expf(-val));
    }

    __shared__ float red[256];
    red[threadIdx.x] = acc;
    __syncthreads();
    if (threadIdx.x < FF) {
        float s = 0.f;
        for (int t = threadIdx.x; t < 256; t += FF) s += red[t];
        ys_part[(sub * NGROUP + g) * FF + threadIdx.x] = s * (1.0f / PP);
    }
}

// ---------------------------------------------------------------------------
// Kernel 4: MLP head; sums the 32 ys partials while loading syr.
// ---------------------------------------------------------------------------
__global__ __launch_bounds__(256) void head_kernel(
    const float* __restrict__ ys_part, const float* __restrict__ W1,
    const float* __restrict__ b1, const float* __restrict__ W2,
    const float* __restrict__ b2, float* __restrict__ out) {
    int g = blockIdx.x;
    __shared__ float syr[FF];
    __shared__ float h[256];
    __shared__ float logits[NCLS];
    __shared__ float mstat[2];
    if (threadIdx.x < FF) {
        float s = 0.f;
#pragma unroll
        for (int sub = 0; sub < YSPLIT; sub++)
            s += ys_part[(sub * NGROUP + g) * FF + threadIdx.x];
        syr[threadIdx.x] = s;
    }
    __syncthreads();
    int j = threadIdx.x;
    float acc = b1[j];
#pragma unroll
    for (int f = 0; f < FF; f++) acc += syr[f] * W1[f * 256 + j];
    h[j] = acc > 0.f ? acc : expm1f(acc);
    __syncthreads();
    if (j < NCLS) {
        float l = b2[j];
        for (int q = 0; q < 256; q++) l += h[q] * W2[q * NCLS + j];
        logits[j] = l;
    }
    __syncthreads();
    if (j == 0) {
        float m = -INFINITY;
        for (int o = 0; o < NCLS; o++) m = fmaxf(m, logits[o]);
        float s = 0.f;
        for (int o = 0; o < NCLS; o++) s += expf(logits[o] - m);
        mstat[0] = m;
        mstat[1] = logf(s);
    }
    __syncthreads();
    if (j < NCLS) out[g * NCLS + j] = logits[j] - mstat[0] - mstat[1];
}

// ---------------------------------------------------------------------------
extern "C" void kernel_launch(void* const* d_in, const int* in_sizes, int n_in,
                              void* d_out, int out_size, void* d_ws, size_t ws_size,
                              hipStream_t stream) {
    const float* pos   = (const float*)d_in[0];
    const float* Wsp   = (const float*)d_in[1];
    const float* root  = (const float*)d_in[2];
    const float* bias  = (const float*)d_in[3];
    const float* gamma = (const float*)d_in[4];
    const float* beta  = (const float*)d_in[5];
    const float* W1    = (const float*)d_in[6];
    const float* b1    = (const float*)d_in[7];
    const float* W2    = (const float*)d_in[8];
    const float* b2    = (const float*)d_in[9];
    float* out = (float*)d_out;

    char* ws = (char*)d_ws;
    float* sums_part = (float*)(ws + 1310720);         // 256*64*4 = 65536
    float* ys_part   = (float*)(ws + 1835008);         // 32*24*32*4 = 98304
    float* sums_accum = (float*)(ws + 1933312);        // 64*4 = 256
    float* node = (float*)(ws + 2621440);              // 32768*32*4 = 4194304
    float* v3   = (float*)(ws + 6815744);              // 32768*3*4  = 393216

    knn_kernel<<<KBLKS, KTHR, 0, stream>>>(pos, Wsp, root, bias, node,
                                           sums_part, v3);
    stats_kernel<<<64, 256, 0, stream>>>(sums_part, sums_accum);
    ys_kernel<<<NGROUP * YSPLIT, 256, 0, stream>>>(node, v3, sums_accum, gamma,
                                                   beta, ys_part);
    head_kernel<<<NGROUP, 256, 0, stream>>>(ys_part, W1, b1, W2, b2, out);
}